// Round 13
// baseline (57.637 us; speedup 1.0000x reference)
//
#include <hip/hip_runtime.h>
#include <hip/hip_bf16.h>

namespace {

constexpr int kN = 8192;
constexpr float kScale = 0.35355339059327373f;  // 1/sqrt(D=8)

typedef __attribute__((ext_vector_type(8))) short short8;
typedef __attribute__((ext_vector_type(4))) float f32x4;
using uint = unsigned int;

// HW bf16 RNE: scalar casts -> compiler fuses pairs into v_cvt_pk_bf16_f32
__device__ __forceinline__ uint pack2(float lo, float hi) {
  const unsigned short a =
      __builtin_bit_cast(unsigned short, __float2bfloat16(lo));
  const unsigned short b =
      __builtin_bit_cast(unsigned short, __float2bfloat16(hi));
  return (uint)a | ((uint)b << 16);
}
__device__ __forceinline__ float sx(float v, int m) {
  return __shfl_xor(v, m, 64);
}

// R11 (54.6us) + cross-point prefetch AT 3 WAVES/SIMD.
// Why this differs from the failed R5-R7 prefetches: those ran at
// __launch_bounds__(256,4), where the unified register file splits as
// 64 AGPR (rounded) + 64 VGPR -- every spilled round reported VGPR_Count=64.
// Body(~64) + 32-reg prefetch cannot fit in 64 VGPRs -> scratch. At
// (256,3) the budget is ~170: ~106 VGPR + 64 AGPR; body+prefetch ~= 96 fits.
// Second enabler: the in-loop fence is a RAW s_barrier (no vmcnt drain).
// __syncthreads forces s_waitcnt vmcnt(0) first (m97), which would kill any
// load crossing the iteration boundary; the raw builtin keeps the pacing
// without the drain, so the prefetched loads stay in flight across it.
// Kept: pl = i*4+wave interleave, phased K/V GEMMs (32 AGPR), deferred
// full-line epilogue, setprio around MFMA clusters.
__global__ __launch_bounds__(256, 3) void ca_mfma11(
    const float* __restrict__ pcd, const float* __restrict__ nbr,
    const float* __restrict__ q_w, const float* __restrict__ k_w,
    const float* __restrict__ v_w, float* __restrict__ out) {
  __shared__ alignas(16) ushort w_lds[2][64][64];  // [W][o][c] bf16, swizzled
  __shared__ alignas(16) float q_lds[16 * 68];     // [point][o], pre-scaled
  __shared__ alignas(16) float x_lds[16][68];      // [point][o]

  const int t = threadIdx.x, wave = t >> 6, lane = t & 63;
  const int l15 = lane & 15, g = lane >> 4;
  const int chunk = blockIdx.x;
  const int b = chunk >> 9;  // 512 chunks per batch
  const int n0 = (chunk & 511) * 16;

  const float* nbase = nbr + (size_t)b * 16777216;  // [c][n][k], c-stride 262144

  // ---- prologue: issue first point's 32 gathers before weight staging ----
  float bl[2][2][8];  // [ks][nt][j]; const-indexed register array
  {
    const float* nb = nbase + (size_t)(n0 + wave) * 32;
#pragma unroll
    for (int ks = 0; ks < 2; ++ks)
#pragma unroll
      for (int nt = 0; nt < 2; ++nt)
#pragma unroll
        for (int j = 0; j < 8; ++j)
          bl[ks][nt][j] =
              nb[(size_t)(ks * 32 + g * 8 + j) * 262144 + nt * 16 + l15];
  }

  // ---- one-time: stage k_w/v_w to LDS (1024 tasks, 4 per thread) ----
#pragma unroll
  for (int it = 0; it < 4; ++it) {
    const int task = it * 256 + t;
    const int W = task >> 9, m = (task >> 3) & 63, c0 = (task & 7) * 8;
    const float* src = (W ? v_w : k_w) + m * 64 + c0;
    const float4 a = *(const float4*)src;
    const float4 c = *(const float4*)(src + 4);
    const uint4 pk = make_uint4(pack2(a.x, a.y), pack2(a.z, a.w),
                                pack2(c.x, c.y), pack2(c.z, c.w));
    *(uint4*)((char*)&w_lds[W][m][0] + ((c0 * 2) ^ ((m & 7) << 4))) = pk;
  }

  // ---- one-time (wave 0): q = (kScale*q_w) * pcd for 16 points via MFMA ----
  if (wave == 0) {
    short8 bp[2];  // B: lane l15 = point, elems c = ks*32+g*8+j
#pragma unroll
    for (int ks = 0; ks < 2; ++ks) {
      float pv[8];
#pragma unroll
      for (int j = 0; j < 8; ++j)
        pv[j] = pcd[((size_t)b * 64 + ks * 32 + g * 8 + j) * kN + n0 + l15];
      const uint4 u = make_uint4(pack2(pv[0], pv[1]), pack2(pv[2], pv[3]),
                                 pack2(pv[4], pv[5]), pack2(pv[6], pv[7]));
      bp[ks] = *(const short8*)&u;
    }
    f32x4 cq[4] = {};
#pragma unroll
    for (int ks = 0; ks < 2; ++ks) {
#pragma unroll
      for (int mt = 0; mt < 4; ++mt) {
        const float* qs = q_w + (mt * 16 + l15) * 64 + ks * 32 + g * 8;
        const float4 qa = *(const float4*)qs;
        const float4 qb = *(const float4*)(qs + 4);
        const uint4 u = make_uint4(pack2(qa.x * kScale, qa.y * kScale),
                                   pack2(qa.z * kScale, qa.w * kScale),
                                   pack2(qb.x * kScale, qb.y * kScale),
                                   pack2(qb.z * kScale, qb.w * kScale));
        const short8 aq = *(const short8*)&u;
        cq[mt] =
            __builtin_amdgcn_mfma_f32_16x16x32_bf16(aq, bp[ks], cq[mt], 0, 0, 0);
      }
    }
    // C: lane holds q[o = mt*16 + g*4 + r][point = l15]
#pragma unroll
    for (int mt = 0; mt < 4; ++mt)
      *(f32x4*)&q_lds[l15 * 68 + mt * 16 + g * 4] = cq[mt];
  }
  __syncthreads();  // full barrier: w_lds/q_lds visible to all waves

  const int swz = (l15 & 7) << 4;

  // ---- 4 iterations; wave w owns point n0 + i*4 + w ----
  for (int i = 0; i < 4; ++i) {
    const int pl = i * 4 + wave;

    // pack current point's B fragments (frees bl for the prefetch)
    short8 bf[2][2];
#pragma unroll
    for (int ks = 0; ks < 2; ++ks)
#pragma unroll
      for (int nt = 0; nt < 2; ++nt) {
        const uint4 u = make_uint4(pack2(bl[ks][nt][0], bl[ks][nt][1]),
                                   pack2(bl[ks][nt][2], bl[ks][nt][3]),
                                   pack2(bl[ks][nt][4], bl[ks][nt][5]),
                                   pack2(bl[ks][nt][6], bl[ks][nt][7]));
        bf[ks][nt] = *(const short8*)&u;
      }

    // issue next point's 32 gathers: fly under K-GEMM..V-GEMM..fold and
    // across the raw barrier (no vmcnt drain) into the next iteration
    if (i < 3) {
      const float* nbn = nbase + (size_t)(n0 + pl + 4) * 32;
#pragma unroll
      for (int ks = 0; ks < 2; ++ks)
#pragma unroll
        for (int nt = 0; nt < 2; ++nt)
#pragma unroll
          for (int j = 0; j < 8; ++j)
            bl[ks][nt][j] =
                nbn[(size_t)(ks * 32 + g * 8 + j) * 262144 + nt * 16 + l15];
    }

    // ---- phase 1: K projection GEMM (only accK live) ----
    f32x4 accK[2][4] = {};
    __builtin_amdgcn_s_setprio(1);
#pragma unroll
    for (int ks = 0; ks < 2; ++ks) {
      const int cb = ks * 64 + g * 16;
#pragma unroll
      for (int mt = 0; mt < 4; ++mt) {
        const short8 af = *(const short8*)(
            (const char*)&w_lds[0][mt * 16 + l15][0] + (cb ^ swz));
#pragma unroll
        for (int nt = 0; nt < 2; ++nt)
          accK[nt][mt] = __builtin_amdgcn_mfma_f32_16x16x32_bf16(
              af, bf[ks][nt], accK[nt][mt], 0, 0, 0);
      }
    }
    __builtin_amdgcn_s_setprio(0);

    // C layout: lane holds C[m = mt*16 + g*4 + r][k = nt*16 + l15]
    // energy + exp (no max-sub: unit-normal inputs keep |e| small; exact math)
    float p_[4][2], ps[4];
#pragma unroll
    for (int mt = 0; mt < 4; ++mt) {
      const f32x4 qv = *(const f32x4*)&q_lds[pl * 68 + mt * 16 + g * 4];
#pragma unroll
      for (int nt = 0; nt < 2; ++nt) {
        float part = qv.x * accK[nt][mt][0] + qv.y * accK[nt][mt][1] +
                     qv.z * accK[nt][mt][2] + qv.w * accK[nt][mt][3];
        p_[mt][nt] = __expf(part + sx(part, 16));  // d-halves meet at g^1
      }
      ps[mt] = p_[mt][0] + p_[mt][1];
    }
    // accK dead from here -> the V accumulator reuses its registers

    // denominator fold: 4 sums over 16 lanes -> lane holds its head's sum
    const bool b8 = (l15 & 8) != 0, b4 = (l15 & 4) != 0;
    float s0 = (b8 ? ps[2] : ps[0]) + sx(b8 ? ps[0] : ps[2], 8);
    float s1 = (b8 ? ps[3] : ps[1]) + sx(b8 ? ps[1] : ps[3], 8);
    float sm = (b4 ? s1 : s0) + sx(b4 ? s0 : s1, 4);
    sm += sx(sm, 2);
    sm += sx(sm, 1);

    // ---- phase 2: V projection GEMM (reuses accumulator registers) ----
    f32x4 accV[2][4] = {};
    __builtin_amdgcn_s_setprio(1);
#pragma unroll
    for (int ks = 0; ks < 2; ++ks) {
      const int cb = ks * 64 + g * 16;
#pragma unroll
      for (int mt = 0; mt < 4; ++mt) {
        const short8 af = *(const short8*)(
            (const char*)&w_lds[1][mt * 16 + l15][0] + (cb ^ swz));
#pragma unroll
        for (int nt = 0; nt < 2; ++nt)
          accV[nt][mt] = __builtin_amdgcn_mfma_f32_16x16x32_bf16(
              af, bf[ks][nt], accV[nt][mt], 0, 0, 0);
      }
    }
    __builtin_amdgcn_s_setprio(0);

    // PV (unnormalized), then fold 16 values over 16 lanes
    float xv[16];
#pragma unroll
    for (int mt = 0; mt < 4; ++mt)
#pragma unroll
      for (int r = 0; r < 4; ++r)
        xv[mt * 4 + r] =
            p_[mt][0] * accV[0][mt][r] + p_[mt][1] * accV[1][mt][r];
    float a8[8];
#pragma unroll
    for (int j = 0; j < 8; ++j)
      a8[j] = (b8 ? xv[j + 8] : xv[j]) + sx(b8 ? xv[j] : xv[j + 8], 8);
    float a4[4];
#pragma unroll
    for (int j = 0; j < 4; ++j)
      a4[j] = (b4 ? a8[j + 4] : a8[j]) + sx(b4 ? a8[j] : a8[j + 4], 4);
    const bool b2 = (l15 & 2) != 0, b1 = (l15 & 1) != 0;
    float a2[2];
#pragma unroll
    for (int j = 0; j < 2; ++j)
      a2[j] = (b2 ? a4[j + 2] : a4[j]) + sx(b2 ? a4[j] : a4[j + 2], 2);
    const float x1 = (b1 ? a2[1] : a2[0]) + sx(b1 ? a2[0] : a2[1], 1);

    // lane holds x[m = (l15>>2)*16 + g*4 + (l15&3)]; wave-private row
    x_lds[pl][(l15 >> 2) * 16 + g * 4 + (l15 & 3)] =
        x1 * __builtin_amdgcn_rcpf(sm);

    // raw barrier: wave pacing WITHOUT the vmcnt drain __syncthreads implies
    __builtin_amdgcn_s_barrier();
  }

  __syncthreads();  // full barrier: cross-wave x_lds handoff for epilogue

  // ---- epilogue: full-line stores; (o,seg) -> float4 over n ----
  {
    const int o = t >> 2, seg = t & 3;
    float4 r;
    r.x = x_lds[seg * 4 + 0][o];
    r.y = x_lds[seg * 4 + 1][o];
    r.z = x_lds[seg * 4 + 2][o];
    r.w = x_lds[seg * 4 + 3][o];
    *(float4*)&out[((size_t)b * 64 + o) * kN + n0 + seg * 4] = r;
  }
}

}  // namespace

extern "C" void kernel_launch(void* const* d_in, const int* in_sizes, int n_in,
                              void* d_out, int out_size, void* d_ws,
                              size_t ws_size, hipStream_t stream) {
  const float* pcd = (const float*)d_in[0];
  const float* nbr = (const float*)d_in[1];
  const float* q_w = (const float*)d_in[2];
  const float* k_w = (const float*)d_in[3];
  const float* v_w = (const float*)d_in[4];
  float* out = (float*)d_out;

  const dim3 grid(2048);  // 32768 points / 16 per WG
  const dim3 block(256);
  hipLaunchKernelGGL(ca_mfma11, grid, block, 0, stream, pcd, nbr, q_w, k_w,
                     v_w, out);
}

// Round 14
// 54.460 us; speedup vs baseline: 1.0583x; 1.0583x over previous
//
#include <hip/hip_runtime.h>
#include <hip/hip_bf16.h>

namespace {

constexpr int kN = 8192;
constexpr float kScale = 0.35355339059327373f;  // 1/sqrt(D=8)

typedef __attribute__((ext_vector_type(8))) short short8;
typedef __attribute__((ext_vector_type(4))) float f32x4;
using uint = unsigned int;

// HW bf16 RNE: scalar casts -> compiler fuses pairs into v_cvt_pk_bf16_f32
__device__ __forceinline__ uint pack2(float lo, float hi) {
  const unsigned short a =
      __builtin_bit_cast(unsigned short, __float2bfloat16(lo));
  const unsigned short b =
      __builtin_bit_cast(unsigned short, __float2bfloat16(hi));
  return (uint)a | ((uint)b << 16);
}
__device__ __forceinline__ float sx(float v, int m) {
  return __shfl_xor(v, m, 64);
}

// FINAL: revert to R11 (54.58us, best measured). Structure: one wave owns one
// point per iteration (pl = i*4+wave interleave -> the 4 waves' gathers cover
// adjacent 128B segments in lockstep); per-point 64x32 neighbor tile gathered
// straight to registers, bf16-packed via HW cvt_pk, projected through K/V
// MFMA GEMMs (phased: one 32-reg accumulator live at a time) against
// LDS-staged swizzled bf16 weights; softmax + PV entirely in registers via
// shfl_xor fold-trees (no max-sub: unit-normal inputs); per-iteration
// __syncthreads fence (prevents cross-iteration gather hoisting -> spill;
// R5-R9 each violated this once, each time 100-580MB scratch traffic);
// deferred full-line float4 epilogue.
// Measured flat band R11/R12/R13 = 54.6/56.0/57.6us across +occupancy /
// -VMEM-count / +prefetch: memory-pattern roofline at ~5 TB/s combined
// HBM+L3 service for the layout-forced 128B-granular gather.
__global__ __launch_bounds__(256, 5) void ca_mfma9(
    const float* __restrict__ pcd, const float* __restrict__ nbr,
    const float* __restrict__ q_w, const float* __restrict__ k_w,
    const float* __restrict__ v_w, float* __restrict__ out) {
  __shared__ alignas(16) ushort w_lds[2][64][64];  // [W][o][c] bf16, swizzled
  __shared__ alignas(16) float q_lds[16 * 68];     // [point][o], pre-scaled
  __shared__ alignas(16) float x_lds[16][68];      // [point][o]

  const int t = threadIdx.x, wave = t >> 6, lane = t & 63;
  const int l15 = lane & 15, g = lane >> 4;
  const int chunk = blockIdx.x;
  const int b = chunk >> 9;  // 512 chunks per batch
  const int n0 = (chunk & 511) * 16;

  // ---- one-time: stage k_w/v_w to LDS (1024 tasks, 4 per thread) ----
#pragma unroll
  for (int it = 0; it < 4; ++it) {
    const int task = it * 256 + t;
    const int W = task >> 9, m = (task >> 3) & 63, c0 = (task & 7) * 8;
    const float* src = (W ? v_w : k_w) + m * 64 + c0;
    const float4 a = *(const float4*)src;
    const float4 c = *(const float4*)(src + 4);
    const uint4 pk = make_uint4(pack2(a.x, a.y), pack2(a.z, a.w),
                                pack2(c.x, c.y), pack2(c.z, c.w));
    *(uint4*)((char*)&w_lds[W][m][0] + ((c0 * 2) ^ ((m & 7) << 4))) = pk;
  }

  // ---- one-time (wave 0): q = (kScale*q_w) * pcd for 16 points via MFMA ----
  if (wave == 0) {
    short8 bp[2];  // B: lane l15 = point, elems c = ks*32+g*8+j
#pragma unroll
    for (int ks = 0; ks < 2; ++ks) {
      float pv[8];
#pragma unroll
      for (int j = 0; j < 8; ++j)
        pv[j] = pcd[((size_t)b * 64 + ks * 32 + g * 8 + j) * kN + n0 + l15];
      const uint4 u = make_uint4(pack2(pv[0], pv[1]), pack2(pv[2], pv[3]),
                                 pack2(pv[4], pv[5]), pack2(pv[6], pv[7]));
      bp[ks] = *(const short8*)&u;
    }
    f32x4 cq[4] = {};
#pragma unroll
    for (int ks = 0; ks < 2; ++ks) {
#pragma unroll
      for (int mt = 0; mt < 4; ++mt) {
        const float* qs = q_w + (mt * 16 + l15) * 64 + ks * 32 + g * 8;
        const float4 qa = *(const float4*)qs;
        const float4 qb = *(const float4*)(qs + 4);
        const uint4 u = make_uint4(pack2(qa.x * kScale, qa.y * kScale),
                                   pack2(qa.z * kScale, qa.w * kScale),
                                   pack2(qb.x * kScale, qb.y * kScale),
                                   pack2(qb.z * kScale, qb.w * kScale));
        const short8 aq = *(const short8*)&u;
        cq[mt] =
            __builtin_amdgcn_mfma_f32_16x16x32_bf16(aq, bp[ks], cq[mt], 0, 0, 0);
      }
    }
    // C: lane holds q[o = mt*16 + g*4 + r][point = l15]
#pragma unroll
    for (int mt = 0; mt < 4; ++mt)
      *(f32x4*)&q_lds[l15 * 68 + mt * 16 + g * 4] = cq[mt];
  }
  __syncthreads();

  // ---- 4 iterations; wave w owns point n0 + i*4 + w ----
  for (int i = 0; i < 4; ++i) {
    const int pl = i * 4 + wave;
    const int n = n0 + pl;

    // gather this point's 64x32 neighbor tile as B-fragment sources
    float bl[2][2][8];
    const size_t pb = (size_t)b * 16777216 + (size_t)n * 32;
#pragma unroll
    for (int ks = 0; ks < 2; ++ks)
#pragma unroll
      for (int nt = 0; nt < 2; ++nt)
#pragma unroll
        for (int j = 0; j < 8; ++j)
          bl[ks][nt][j] =
              nbr[pb + (size_t)(ks * 32 + g * 8 + j) * 262144 + nt * 16 + l15];

    short8 bf[2][2];
#pragma unroll
    for (int ks = 0; ks < 2; ++ks)
#pragma unroll
      for (int nt = 0; nt < 2; ++nt) {
        const uint4 u = make_uint4(pack2(bl[ks][nt][0], bl[ks][nt][1]),
                                   pack2(bl[ks][nt][2], bl[ks][nt][3]),
                                   pack2(bl[ks][nt][4], bl[ks][nt][5]),
                                   pack2(bl[ks][nt][6], bl[ks][nt][7]));
        bf[ks][nt] = *(const short8*)&u;
      }

    const int swz = (l15 & 7) << 4;

    // ---- phase 1: K projection GEMM (only accK live) ----
    f32x4 accK[2][4] = {};
    __builtin_amdgcn_s_setprio(1);
#pragma unroll
    for (int ks = 0; ks < 2; ++ks) {
      const int cb = ks * 64 + g * 16;
#pragma unroll
      for (int mt = 0; mt < 4; ++mt) {
        const short8 af = *(const short8*)(
            (const char*)&w_lds[0][mt * 16 + l15][0] + (cb ^ swz));
#pragma unroll
        for (int nt = 0; nt < 2; ++nt)
          accK[nt][mt] = __builtin_amdgcn_mfma_f32_16x16x32_bf16(
              af, bf[ks][nt], accK[nt][mt], 0, 0, 0);
      }
    }
    __builtin_amdgcn_s_setprio(0);

    // C layout: lane holds C[m = mt*16 + g*4 + r][k = nt*16 + l15]
    // energy + exp (no max-sub: unit-normal inputs keep |e| small; exact math)
    float p_[4][2], ps[4];
#pragma unroll
    for (int mt = 0; mt < 4; ++mt) {
      const f32x4 qv = *(const f32x4*)&q_lds[pl * 68 + mt * 16 + g * 4];
#pragma unroll
      for (int nt = 0; nt < 2; ++nt) {
        float part = qv.x * accK[nt][mt][0] + qv.y * accK[nt][mt][1] +
                     qv.z * accK[nt][mt][2] + qv.w * accK[nt][mt][3];
        p_[mt][nt] = __expf(part + sx(part, 16));  // d-halves meet at g^1
      }
      ps[mt] = p_[mt][0] + p_[mt][1];
    }
    // accK dead from here -> the V accumulator reuses its registers

    // denominator fold: 4 sums over 16 lanes -> lane holds its head's sum
    const bool b8 = (l15 & 8) != 0, b4 = (l15 & 4) != 0;
    float s0 = (b8 ? ps[2] : ps[0]) + sx(b8 ? ps[0] : ps[2], 8);
    float s1 = (b8 ? ps[3] : ps[1]) + sx(b8 ? ps[1] : ps[3], 8);
    float sm = (b4 ? s1 : s0) + sx(b4 ? s0 : s1, 4);
    sm += sx(sm, 2);
    sm += sx(sm, 1);

    // ---- phase 2: V projection GEMM (reuses accumulator registers) ----
    f32x4 accV[2][4] = {};
    __builtin_amdgcn_s_setprio(1);
#pragma unroll
    for (int ks = 0; ks < 2; ++ks) {
      const int cb = ks * 64 + g * 16;
#pragma unroll
      for (int mt = 0; mt < 4; ++mt) {
        const short8 af = *(const short8*)(
            (const char*)&w_lds[1][mt * 16 + l15][0] + (cb ^ swz));
#pragma unroll
        for (int nt = 0; nt < 2; ++nt)
          accV[nt][mt] = __builtin_amdgcn_mfma_f32_16x16x32_bf16(
              af, bf[ks][nt], accV[nt][mt], 0, 0, 0);
      }
    }
    __builtin_amdgcn_s_setprio(0);

    // PV (unnormalized), then fold 16 values over 16 lanes
    float xv[16];
#pragma unroll
    for (int mt = 0; mt < 4; ++mt)
#pragma unroll
      for (int r = 0; r < 4; ++r)
        xv[mt * 4 + r] =
            p_[mt][0] * accV[0][mt][r] + p_[mt][1] * accV[1][mt][r];
    float a8[8];
#pragma unroll
    for (int j = 0; j < 8; ++j)
      a8[j] = (b8 ? xv[j + 8] : xv[j]) + sx(b8 ? xv[j] : xv[j + 8], 8);
    float a4[4];
#pragma unroll
    for (int j = 0; j < 4; ++j)
      a4[j] = (b4 ? a8[j + 4] : a8[j]) + sx(b4 ? a8[j] : a8[j + 4], 4);
    const bool b2 = (l15 & 2) != 0, b1 = (l15 & 1) != 0;
    float a2[2];
#pragma unroll
    for (int j = 0; j < 2; ++j)
      a2[j] = (b2 ? a4[j + 2] : a4[j]) + sx(b2 ? a4[j] : a4[j + 2], 2);
    const float x1 = (b1 ? a2[1] : a2[0]) + sx(b1 ? a2[0] : a2[1], 1);

    // lane holds x[m = (l15>>2)*16 + g*4 + (l15&3)]; wave-private row
    x_lds[pl][(l15 >> 2) * 16 + g * 4 + (l15 & 3)] =
        x1 * __builtin_amdgcn_rcpf(sm);

    __syncthreads();  // scheduling fence: no gather hoisting, waves lockstep
  }

  // ---- epilogue: full-line stores; (o,seg) -> float4 over n ----
  {
    const int o = t >> 2, seg = t & 3;
    float4 r;
    r.x = x_lds[seg * 4 + 0][o];
    r.y = x_lds[seg * 4 + 1][o];
    r.z = x_lds[seg * 4 + 2][o];
    r.w = x_lds[seg * 4 + 3][o];
    *(float4*)&out[((size_t)b * 64 + o) * kN + n0 + seg * 4] = r;
  }
}

}  // namespace

extern "C" void kernel_launch(void* const* d_in, const int* in_sizes, int n_in,
                              void* d_out, int out_size, void* d_ws,
                              size_t ws_size, hipStream_t stream) {
  const float* pcd = (const float*)d_in[0];
  const float* nbr = (const float*)d_in[1];
  const float* q_w = (const float*)d_in[2];
  const float* k_w = (const float*)d_in[3];
  const float* v_w = (const float*)d_in[4];
  float* out = (float*)d_out;

  const dim3 grid(2048);  // 32768 points / 16 per WG
  const dim3 block(256);
  hipLaunchKernelGGL(ca_mfma9, grid, block, 0, stream, pcd, nbr, q_w, k_w, v_w,
                     out);
}